// Round 2
// baseline (256.093 us; speedup 1.0000x reference)
//
#include <hip/hip_runtime.h>
#include <stdint.h>

#define BATCH 4
#define SEQ   2048
#define HID   1024

typedef __attribute__((ext_vector_type(8))) short bf16x8;
typedef __attribute__((ext_vector_type(4))) float f32x4;

__device__ __forceinline__ uint16_t f2bf(float f) {
    union { float f; uint32_t u; } v; v.f = f;
    uint32_t r = v.u + 0x7fffu + ((v.u >> 16) & 1u);
    return (uint16_t)(r >> 16);
}

__device__ __forceinline__ void async_ld16(const void* g, void* l) {
    __builtin_amdgcn_global_load_lds(
        (const __attribute__((address_space(1))) void*)g,
        (__attribute__((address_space(3))) void*)l,
        16, 0, 0);
}

// ---------------- fp32 -> bf16 convert (8 elems/thread) ----------------
__global__ __launch_bounds__(256) void f32_to_bf16_8(const float* __restrict__ in,
                                                     uint16_t* __restrict__ out) {
    const long i = ((long)blockIdx.x * 256 + threadIdx.x) * 8;
    float4 a = *(const float4*)(in + i);
    float4 b = *(const float4*)(in + i + 4);
    union { uint16_t u[8]; uint4 v; } o;
    o.u[0] = f2bf(a.x); o.u[1] = f2bf(a.y); o.u[2] = f2bf(a.z); o.u[3] = f2bf(a.w);
    o.u[4] = f2bf(b.x); o.u[5] = f2bf(b.y); o.u[6] = f2bf(b.z); o.u[7] = f2bf(b.w);
    *(uint4*)(out + i) = o.v;
}

// ---------------- NT GEMM: C[M,N] = A[M,K] * B[N,K]^T (+bias) ----------------
// A,B bf16 row-major (ld = K). 128x128 tile, BK=32, 4 waves, 16x16x32 MFMA.
template <int OUT_BF16, int HAS_BIAS>
__global__ __launch_bounds__(256)
void gemm_nt(const uint16_t* __restrict__ A, long sA,
             const uint16_t* __restrict__ B, long sB,
             float* __restrict__ Cf, uint16_t* __restrict__ Cb, long sC,
             const float* __restrict__ bias,
             int Nld, int K) {
    __shared__ uint16_t As[128][32];
    __shared__ uint16_t Bs[128][32];

    const int tid  = threadIdx.x;
    const int lane = tid & 63;
    const int wv   = tid >> 6;
    const int bz   = blockIdx.z;

    A += (long)bz * sA;
    B += (long)bz * sB;

    const long m0 = (long)blockIdx.y * 128;
    const long n0 = (long)blockIdx.x * 128;

    // staging: each wave stages 32 rows of A and 32 rows of B (2 x 16-row chunks)
    const int srow = wv * 32 + (lane >> 2);
    const int scol = (lane & 3) * 8;
    const uint16_t* ga = A + (m0 + srow) * (long)K + scol;
    const uint16_t* gb = B + (n0 + srow) * (long)K + scol;
    void* la0 = (void*)&As[wv * 32][0];
    void* la1 = (void*)&As[wv * 32 + 16][0];
    void* lb0 = (void*)&Bs[wv * 32][0];
    void* lb1 = (void*)&Bs[wv * 32 + 16][0];

    const int wr   = (wv >> 1) * 64;   // wave row offset in C tile
    const int wc   = (wv & 1) * 64;    // wave col offset in C tile
    const int quad = lane >> 4;
    const int l16  = lane & 15;

    f32x4 acc[4][4];
#pragma unroll
    for (int i = 0; i < 4; i++)
#pragma unroll
        for (int j = 0; j < 4; j++) acc[i][j] = (f32x4){0.f, 0.f, 0.f, 0.f};

    for (int k0 = 0; k0 < K; k0 += 32) {
        async_ld16(ga + k0,            la0);
        async_ld16(ga + k0 + 16L * K,  la1);
        async_ld16(gb + k0,            lb0);
        async_ld16(gb + k0 + 16L * K,  lb1);
        __syncthreads();
        bf16x8 af[4], bfr[4];
#pragma unroll
        for (int i = 0; i < 4; i++)
            af[i] = *(const bf16x8*)&As[wr + i * 16 + l16][quad * 8];
#pragma unroll
        for (int j = 0; j < 4; j++)
            bfr[j] = *(const bf16x8*)&Bs[wc + j * 16 + l16][quad * 8];
#pragma unroll
        for (int i = 0; i < 4; i++)
#pragma unroll
            for (int j = 0; j < 4; j++)
                acc[i][j] = __builtin_amdgcn_mfma_f32_16x16x32_bf16(af[i], bfr[j], acc[i][j], 0, 0, 0);
        __syncthreads();
    }

    // epilogue: C row = quad*4 + reg, col = lane&15 (per-16x16 tile)
    const int crow = wr + quad * 4;
    const int ccol = wc + l16;
#pragma unroll
    for (int j = 0; j < 4; j++) {
        const long col = n0 + ccol + j * 16;
        float bv = 0.f;
        if (HAS_BIAS) bv = bias[col];
#pragma unroll
        for (int i = 0; i < 4; i++) {
            const long rbase = m0 + crow + i * 16;
#pragma unroll
            for (int r = 0; r < 4; r++) {
                float v = acc[i][j][r] + bv;
                long idx = (long)bz * sC + (rbase + r) * (long)Nld + col;
                if (OUT_BF16) Cb[idx] = f2bf(v);
                else          Cf[idx] = v;
            }
        }
    }
}

// ---------------- bf16 transpose per batch: [SEQ][HID] -> [HID][SEQ] ----------------
// 64x64 tile, 256 threads, 16 elems/thread (two 8-elem halves) in BOTH phases.
__global__ __launch_bounds__(256) void transpose64(const uint16_t* __restrict__ in,
                                                   uint16_t* __restrict__ out) {
    __shared__ uint16_t t[64][72];
    const int b = blockIdx.z;
    in  += (long)b * SEQ * HID;
    out += (long)b * SEQ * HID;
    const int h0 = blockIdx.x * 64;
    const int s0 = blockIdx.y * 64;
    const int tid = threadIdx.x;
    const int r  = tid >> 2;          // 0..63
    const int c0 = (tid & 3) * 8;     // 0,8,16,24
#pragma unroll
    for (int half = 0; half < 2; half++) {
        const int c = c0 + half * 32;
        *(uint4*)&t[r][c] = *(const uint4*)&in[(long)(s0 + r) * HID + h0 + c];
    }
    __syncthreads();
#pragma unroll
    for (int half = 0; half < 2; half++) {
        const int c = c0 + half * 32;
        union { uint16_t u[8]; uint4 v; } o;
#pragma unroll
        for (int j = 0; j < 8; j++) o.u[j] = t[c + j][r];
        *(uint4*)&out[(long)(h0 + r) * SEQ + s0 + c] = o.v;
    }
}

// ---------------- row softmax: fp32 scores[rows][SEQ] -> bf16 probs ----------------
__global__ __launch_bounds__(256) void softmax_rows(const float* __restrict__ S,
                                                    uint16_t* __restrict__ P) {
    const long row = blockIdx.x;
    const float* sr = S + row * (long)SEQ;
    uint16_t* pr = P + row * (long)SEQ;
    const int tid  = threadIdx.x;
    const int lane = tid & 63;
    const int wv   = tid >> 6;
    float4 v0 = *(const float4*)(sr + tid * 8);
    float4 v1 = *(const float4*)(sr + tid * 8 + 4);
    float m = fmaxf(fmaxf(fmaxf(v0.x, v0.y), fmaxf(v0.z, v0.w)),
                    fmaxf(fmaxf(v1.x, v1.y), fmaxf(v1.z, v1.w)));
#pragma unroll
    for (int o = 32; o > 0; o >>= 1) m = fmaxf(m, __shfl_xor(m, o));
    __shared__ float red[8];
    if (lane == 0) red[wv] = m;
    __syncthreads();
    m = fmaxf(fmaxf(red[0], red[1]), fmaxf(red[2], red[3]));
    float e[8];
    e[0] = __expf(v0.x - m); e[1] = __expf(v0.y - m);
    e[2] = __expf(v0.z - m); e[3] = __expf(v0.w - m);
    e[4] = __expf(v1.x - m); e[5] = __expf(v1.y - m);
    e[6] = __expf(v1.z - m); e[7] = __expf(v1.w - m);
    float s = ((e[0] + e[1]) + (e[2] + e[3])) + ((e[4] + e[5]) + (e[6] + e[7]));
#pragma unroll
    for (int o = 32; o > 0; o >>= 1) s += __shfl_xor(s, o);
    if (lane == 0) red[4 + wv] = s;
    __syncthreads();
    s = (red[4] + red[5]) + (red[6] + red[7]);
    const float inv = 1.0f / s;
    union { uint16_t u[8]; uint4 v; } o;
#pragma unroll
    for (int j = 0; j < 8; j++) o.u[j] = f2bf(e[j] * inv);
    *(uint4*)(pr + tid * 8) = o.v;
}

extern "C" void kernel_launch(void* const* d_in, const int* in_sizes, int n_in,
                              void* d_out, int out_size, void* d_ws, size_t ws_size,
                              hipStream_t stream) {
    const float* x    = (const float*)d_in[0];
    const float* W    = (const float*)d_in[1];
    const float* bias = (const float*)d_in[2];
    float* out = (float*)d_out;

    char* w = (char*)d_ws;
    uint16_t* xb   = (uint16_t*)(w);                 // 16,777,216 B
    uint16_t* wb   = (uint16_t*)(w + 16777216);      //  2,097,152 B
    uint16_t* pat  = (uint16_t*)(w + 18874368);      // 16,777,216 B
    uint16_t* patT = (uint16_t*)(w + 35651584);      // 16,777,216 B
    float*    sc   = (float*)   (w + 52428800);      // 67,108,864 B (big) / 16,777,216 (small)
    const size_t need_big = 52428800ull + 67108864ull + 33554432ull;
    const bool big = ws_size >= need_big;
    uint16_t* pb = big ? (uint16_t*)(w + 52428800 + 67108864)
                       : (uint16_t*)(w + 52428800 + 16777216);

    const long PB = (long)SEQ * HID;   // per-batch patterns elems
    const long SB = (long)SEQ * SEQ;   // per-batch scores elems

    // 1) convert inputs to bf16
    f32_to_bf16_8<<<dim3(4096), 256, 0, stream>>>(x, xb);
    f32_to_bf16_8<<<dim3(512),  256, 0, stream>>>(W, wb);

    // 2) patterns = xb * wb^T + bias  [8192 x 1024], K=1024, bf16 out
    gemm_nt<1, 1><<<dim3(HID / 128, (BATCH * SEQ) / 128, 1), 256, 0, stream>>>(
        xb, 0, wb, 0, nullptr, pat, 0, bias, HID, HID);

    // 3) patT[b] = pat[b]^T
    transpose64<<<dim3(HID / 64, SEQ / 64, BATCH), 256, 0, stream>>>(pat, patT);

    if (big) {
        // 4) scores[b] = pat[b] * pat[b]^T  [2048 x 2048], K=1024, fp32 out
        gemm_nt<0, 0><<<dim3(SEQ / 128, SEQ / 128, BATCH), 256, 0, stream>>>(
            pat, PB, pat, PB, sc, nullptr, SB, nullptr, SEQ, HID);
        // 5) softmax rows -> bf16 probs
        softmax_rows<<<dim3(BATCH * SEQ), 256, 0, stream>>>(sc, pb);
        // 6) out[b] = probs[b] * patT[b]^T  [2048 x 1024], K=2048, fp32 out
        gemm_nt<0, 0><<<dim3(HID / 128, SEQ / 128, BATCH), 256, 0, stream>>>(
            pb, SB, patT, PB, out, nullptr, PB, nullptr, HID, SEQ);
    } else {
        for (int b = 0; b < BATCH; b++) {
            gemm_nt<0, 0><<<dim3(SEQ / 128, SEQ / 128, 1), 256, 0, stream>>>(
                pat + b * PB, 0, pat + b * PB, 0, sc, nullptr, 0, nullptr, SEQ, HID);
            softmax_rows<<<dim3(SEQ), 256, 0, stream>>>(sc, pb);
            gemm_nt<0, 0><<<dim3(HID / 128, SEQ / 128, 1), 256, 0, stream>>>(
                pb, 0, patT + b * PB, 0, out + b * PB, nullptr, 0, nullptr, HID, SEQ);
        }
    }
}

// Round 3
// 223.043 us; speedup vs baseline: 1.1482x; 1.1482x over previous
//
#include <hip/hip_runtime.h>
#include <stdint.h>

#define BATCH 4
#define SEQ   2048
#define HID   1024

typedef __attribute__((ext_vector_type(8))) short bf16x8;
typedef __attribute__((ext_vector_type(4))) float f32x4;

__device__ __forceinline__ uint16_t f2bf(float f) {
    union { float f; uint32_t u; } v; v.f = f;
    uint32_t r = v.u + 0x7fffu + ((v.u >> 16) & 1u);
    return (uint16_t)(r >> 16);
}

__device__ __forceinline__ void async_ld16(const void* g, void* l) {
    __builtin_amdgcn_global_load_lds(
        (const __attribute__((address_space(1))) void*)g,
        (__attribute__((address_space(3))) void*)l,
        16, 0, 0);
}

// ---------------- fp32 -> bf16 convert (8 elems/thread) ----------------
__global__ __launch_bounds__(256) void f32_to_bf16_8(const float* __restrict__ in,
                                                     uint16_t* __restrict__ out) {
    const long i = ((long)blockIdx.x * 256 + threadIdx.x) * 8;
    float4 a = *(const float4*)(in + i);
    float4 b = *(const float4*)(in + i + 4);
    union { uint16_t u[8]; uint4 v; } o;
    o.u[0] = f2bf(a.x); o.u[1] = f2bf(a.y); o.u[2] = f2bf(a.z); o.u[3] = f2bf(a.w);
    o.u[4] = f2bf(b.x); o.u[5] = f2bf(b.y); o.u[6] = f2bf(b.z); o.u[7] = f2bf(b.w);
    *(uint4*)(out + i) = o.v;
}

// ---------------- NT GEMM: C[M,N] = A[M,K] * B[N,K]^T (+bias) ----------------
// A,B bf16 row-major (ld = K). 128x128 tile, BK=64, 4 waves, 16x16x32 MFMA.
// LDS layout XOR-swizzled: LDS[r][chunk] = G[r][chunk ^ (r&7)]  (16B chunks)
// -> frag ds_read_b128 is 2-way-per-bank-group max (free), staging stays
//    wave-uniform-base + lane*16 contiguous as global_load_lds requires.
template <int OUT_BF16, int HAS_BIAS>
__global__ __launch_bounds__(256)
void gemm_nt(const uint16_t* __restrict__ A, long sA,
             const uint16_t* __restrict__ B, long sB,
             float* __restrict__ Cf, uint16_t* __restrict__ Cb, long sC,
             const float* __restrict__ bias,
             int Nld, int K) {
    __shared__ uint16_t As[128][64];
    __shared__ uint16_t Bs[128][64];

    const int tid  = threadIdx.x;
    const int lane = tid & 63;
    const int wv   = tid >> 6;
    const int bz   = blockIdx.z;

    A += (long)bz * sA;
    B += (long)bz * sB;

    const long m0 = (long)blockIdx.y * 128;
    const long n0 = (long)blockIdx.x * 128;

    // staging: per instruction t, one wave covers 8 rows x 8 chunks (64 lanes).
    // lane -> row_local = lane>>3, chunk_lds = lane&7; global chunk = chunk_lds ^ (row&7)
    const int srow8 = lane >> 3;                    // 0..7
    const int scol  = (((lane & 7) ^ srow8) << 3);  // swizzled global col (elems)
    const uint16_t* ga = A + (m0 + wv * 32 + srow8) * (long)K + scol;
    const uint16_t* gb = B + (n0 + wv * 32 + srow8) * (long)K + scol;

    const int wr   = (wv >> 1) * 64;   // wave row offset in C tile
    const int wc   = (wv & 1) * 64;    // wave col offset in C tile
    const int quad = lane >> 4;
    const int l16  = lane & 15;
    const int xr   = l16 & 7;          // row&7 for frag rows (wr,i*16 are mult of 8)

    f32x4 acc[4][4];
#pragma unroll
    for (int i = 0; i < 4; i++)
#pragma unroll
        for (int j = 0; j < 4; j++) acc[i][j] = (f32x4){0.f, 0.f, 0.f, 0.f};

    for (int k0 = 0; k0 < K; k0 += 64) {
#pragma unroll
        for (int t = 0; t < 4; t++) {
            async_ld16(ga + k0 + (long)t * 8 * K, (void*)&As[wv * 32 + t * 8][0]);
            async_ld16(gb + k0 + (long)t * 8 * K, (void*)&Bs[wv * 32 + t * 8][0]);
        }
        __syncthreads();
#pragma unroll
        for (int h = 0; h < 2; h++) {
            bf16x8 af[4], bfr[4];
#pragma unroll
            for (int i = 0; i < 4; i++)
                af[i] = *(const bf16x8*)&As[wr + i * 16 + l16][((h * 4 + quad) ^ xr) << 3];
#pragma unroll
            for (int j = 0; j < 4; j++)
                bfr[j] = *(const bf16x8*)&Bs[wc + j * 16 + l16][((h * 4 + quad) ^ xr) << 3];
#pragma unroll
            for (int i = 0; i < 4; i++)
#pragma unroll
                for (int j = 0; j < 4; j++)
                    acc[i][j] = __builtin_amdgcn_mfma_f32_16x16x32_bf16(af[i], bfr[j], acc[i][j], 0, 0, 0);
        }
        __syncthreads();
    }

    // epilogue: C row = quad*4 + reg, col = lane&15 (per-16x16 tile)
    const int crow = wr + quad * 4;
    const int ccol = wc + l16;
#pragma unroll
    for (int j = 0; j < 4; j++) {
        const long col = n0 + ccol + j * 16;
        float bv = 0.f;
        if (HAS_BIAS) bv = bias[col];
#pragma unroll
        for (int i = 0; i < 4; i++) {
            const long rbase = m0 + crow + i * 16;
#pragma unroll
            for (int r = 0; r < 4; r++) {
                float v = acc[i][j][r] + bv;
                long idx = (long)bz * sC + (rbase + r) * (long)Nld + col;
                if (OUT_BF16) Cb[idx] = f2bf(v);
                else          Cf[idx] = v;
            }
        }
    }
}

// ---------------- bf16 transpose per batch: [SEQ][HID] -> [HID][SEQ] ----------------
// 64x64 tile, 256 threads, 16 elems/thread (two 8-elem halves) in BOTH phases.
__global__ __launch_bounds__(256) void transpose64(const uint16_t* __restrict__ in,
                                                   uint16_t* __restrict__ out) {
    __shared__ uint16_t t[64][72];
    const int b = blockIdx.z;
    in  += (long)b * SEQ * HID;
    out += (long)b * SEQ * HID;
    const int h0 = blockIdx.x * 64;
    const int s0 = blockIdx.y * 64;
    const int tid = threadIdx.x;
    const int r  = tid >> 2;          // 0..63
    const int c0 = (tid & 3) * 8;     // 0,8,16,24
#pragma unroll
    for (int half = 0; half < 2; half++) {
        const int c = c0 + half * 32;
        *(uint4*)&t[r][c] = *(const uint4*)&in[(long)(s0 + r) * HID + h0 + c];
    }
    __syncthreads();
#pragma unroll
    for (int half = 0; half < 2; half++) {
        const int c = c0 + half * 32;
        union { uint16_t u[8]; uint4 v; } o;
#pragma unroll
        for (int j = 0; j < 8; j++) o.u[j] = t[c + j][r];
        *(uint4*)&out[(long)(h0 + r) * SEQ + s0 + c] = o.v;
    }
}

// ---------------- row softmax: fp32 scores[rows][SEQ] -> bf16 probs ----------------
__global__ __launch_bounds__(256) void softmax_rows(const float* __restrict__ S,
                                                    uint16_t* __restrict__ P) {
    const long row = blockIdx.x;
    const float* sr = S + row * (long)SEQ;
    uint16_t* pr = P + row * (long)SEQ;
    const int tid  = threadIdx.x;
    const int lane = tid & 63;
    const int wv   = tid >> 6;
    float4 v0 = *(const float4*)(sr + tid * 8);
    float4 v1 = *(const float4*)(sr + tid * 8 + 4);
    float m = fmaxf(fmaxf(fmaxf(v0.x, v0.y), fmaxf(v0.z, v0.w)),
                    fmaxf(fmaxf(v1.x, v1.y), fmaxf(v1.z, v1.w)));
#pragma unroll
    for (int o = 32; o > 0; o >>= 1) m = fmaxf(m, __shfl_xor(m, o));
    __shared__ float red[8];
    if (lane == 0) red[wv] = m;
    __syncthreads();
    m = fmaxf(fmaxf(red[0], red[1]), fmaxf(red[2], red[3]));
    float e[8];
    e[0] = __expf(v0.x - m); e[1] = __expf(v0.y - m);
    e[2] = __expf(v0.z - m); e[3] = __expf(v0.w - m);
    e[4] = __expf(v1.x - m); e[5] = __expf(v1.y - m);
    e[6] = __expf(v1.z - m); e[7] = __expf(v1.w - m);
    float s = ((e[0] + e[1]) + (e[2] + e[3])) + ((e[4] + e[5]) + (e[6] + e[7]));
#pragma unroll
    for (int o = 32; o > 0; o >>= 1) s += __shfl_xor(s, o);
    if (lane == 0) red[4 + wv] = s;
    __syncthreads();
    s = (red[4] + red[5]) + (red[6] + red[7]);
    const float inv = 1.0f / s;
    union { uint16_t u[8]; uint4 v; } o;
#pragma unroll
    for (int j = 0; j < 8; j++) o.u[j] = f2bf(e[j] * inv);
    *(uint4*)(pr + tid * 8) = o.v;
}

extern "C" void kernel_launch(void* const* d_in, const int* in_sizes, int n_in,
                              void* d_out, int out_size, void* d_ws, size_t ws_size,
                              hipStream_t stream) {
    const float* x    = (const float*)d_in[0];
    const float* W    = (const float*)d_in[1];
    const float* bias = (const float*)d_in[2];
    float* out = (float*)d_out;

    char* w = (char*)d_ws;
    uint16_t* xb   = (uint16_t*)(w);                 // 16,777,216 B
    uint16_t* wb   = (uint16_t*)(w + 16777216);      //  2,097,152 B
    uint16_t* pat  = (uint16_t*)(w + 18874368);      // 16,777,216 B
    uint16_t* patT = (uint16_t*)(w + 35651584);      // 16,777,216 B
    float*    sc   = (float*)   (w + 52428800);      // 67,108,864 B (big) / 16,777,216 (small)
    const size_t need_big = 52428800ull + 67108864ull + 33554432ull;
    const bool big = ws_size >= need_big;
    uint16_t* pb = big ? (uint16_t*)(w + 52428800 + 67108864)
                       : (uint16_t*)(w + 52428800 + 16777216);

    const long PB = (long)SEQ * HID;   // per-batch patterns elems
    const long SB = (long)SEQ * SEQ;   // per-batch scores elems

    // 1) convert inputs to bf16
    f32_to_bf16_8<<<dim3(4096), 256, 0, stream>>>(x, xb);
    f32_to_bf16_8<<<dim3(512),  256, 0, stream>>>(W, wb);

    // 2) patterns = xb * wb^T + bias  [8192 x 1024], K=1024, bf16 out
    gemm_nt<1, 1><<<dim3(HID / 128, (BATCH * SEQ) / 128, 1), 256, 0, stream>>>(
        xb, 0, wb, 0, nullptr, pat, 0, bias, HID, HID);

    // 3) patT[b] = pat[b]^T
    transpose64<<<dim3(HID / 64, SEQ / 64, BATCH), 256, 0, stream>>>(pat, patT);

    if (big) {
        // 4) scores[b] = pat[b] * pat[b]^T  [2048 x 2048], K=1024, fp32 out
        gemm_nt<0, 0><<<dim3(SEQ / 128, SEQ / 128, BATCH), 256, 0, stream>>>(
            pat, PB, pat, PB, sc, nullptr, SB, nullptr, SEQ, HID);
        // 5) softmax rows -> bf16 probs
        softmax_rows<<<dim3(BATCH * SEQ), 256, 0, stream>>>(sc, pb);
        // 6) out[b] = probs[b] * patT[b]^T  [2048 x 1024], K=2048, fp32 out
        gemm_nt<0, 0><<<dim3(HID / 128, SEQ / 128, BATCH), 256, 0, stream>>>(
            pb, SB, patT, PB, out, nullptr, PB, nullptr, HID, SEQ);
    } else {
        for (int b = 0; b < BATCH; b++) {
            gemm_nt<0, 0><<<dim3(SEQ / 128, SEQ / 128, 1), 256, 0, stream>>>(
                pat + b * PB, 0, pat + b * PB, 0, sc, nullptr, 0, nullptr, SEQ, HID);
            softmax_rows<<<dim3(SEQ), 256, 0, stream>>>(sc, pb);
            gemm_nt<0, 0><<<dim3(HID / 128, SEQ / 128, 1), 256, 0, stream>>>(
                pb, 0, patT + b * PB, 0, out + b * PB, nullptr, 0, nullptr, HID, SEQ);
        }
    }
}